// Round 9
// baseline (133.877 us; speedup 1.0000x reference)
//
#include <hip/hip_runtime.h>
#include <hip/hip_bf16.h>

typedef __attribute__((ext_vector_type(8))) short short8;
typedef __attribute__((ext_vector_type(4))) float f32x4;

#define IN_DIM 256
#define OUT_DIM 256
#define NB 16                 // padded basis count (13 real + 3 zero)
#define KDIM (IN_DIM * NB)    // 4096
#define TM 128
#define TN 128
#define BK 64                 // 4 i-values per K-step
#define LDA 72                // padded LDS row stride for B tile (bf16)
#define KSPLIT 4
#define IPER (IN_DIM / KSPLIT)   // 64 i-values per block
#define STEPS (IPER / 4)         // 16
#define XP 68                    // Xsh pitch in f32: %4==0 (b128-aligned rows), 4r-mod-32 banks -> <=2-way
#define XBYTES (TM * XP * 4)              // 34816
#define BBYTES (TN * LDA * 2)             // 18432 per buffer
#define LDS_TOTAL (XBYTES + 2 * BBYTES)   // 71680 -> 2 blocks/CU

__device__ __forceinline__ unsigned short f2bf(float f) {
  union { float f; unsigned int u; } v; v.f = f;
  unsigned int r = v.u + 0x7fffu + ((v.u >> 16) & 1u);  // RNE
  return (unsigned short)(r >> 16);
}

__device__ __forceinline__ unsigned pk2(float lo, float hi) {
  // one v_cvt_pk_bf16_f32: lo -> bits[15:0], hi -> bits[31:16]
  union { __hip_bfloat162 h; unsigned u; } cv;
  cv.h = __float22bfloat162_rn(make_float2(lo, hi));
  return cv.u;
}

// Direct-register A-fragment builder for mfma_f32_16x16x32_bf16.
// Lane needs A[m][k0..k0+7] = 8 n-slots (dword window jg = iq*4 + j, j=0..3,
// dword jg covers n=2jg,2jg+1) of the 16-slot spline row at x=xv.
// Nonzeros are b0..b3 at n=c..c+3.
__device__ __forceinline__ short8 make_afrag(float xv, int iq) {
  float xc = fminf(fmaxf(xv, -1.0f), 1.0f - 1e-6f);
  float u = (xc + 1.0f) * 5.0f;            // h = 0.2
  int c = (int)u;
  c = c > 9 ? 9 : (c < 0 ? 0 : c);
  float tt = u - (float)c;
  float omt = 1.0f - tt;
  float t2 = tt * tt, t3 = t2 * tt;
  float b0 = omt * omt * omt * (1.0f / 6.0f);
  float b1 = (3.0f * t3 - 6.0f * t2 + 4.0f) * (1.0f / 6.0f);
  float b2 = (-3.0f * t3 + 3.0f * t2 + 3.0f * tt + 1.0f) * (1.0f / 6.0f);
  float b3 = t3 * (1.0f / 6.0f);
  unsigned p01 = pk2(b0, b1), p23 = pk2(b2, b3);
  unsigned q0 = pk2(0.0f, b0), q12 = pk2(b1, b2), q3 = pk2(b3, 0.0f);
  const bool odd = (c & 1) != 0;
  const int a = c >> 1;                    // first nonzero dword
  unsigned A0 = odd ? q0 : p01;
  unsigned A1 = odd ? q12 : p23;
  unsigned A2 = odd ? q3 : 0u;
  union { unsigned u4[4]; short8 v; } r;
  const int base = iq * 4;
#pragma unroll
  for (int j = 0; j < 4; ++j) {
    int d = base + j - a;
    unsigned v = (d == 0) ? A0 : 0u;
    v = (d == 1) ? A1 : v;
    v = (d == 2) ? A2 : v;
    r.u4[j] = v;
  }
  return r.v;
}

// --- prep: BmT[o][i*16+n] = bf16( sum_e softmax(gating[i,o,:])[e] * coeff[e,n] ); also zeroes out
__global__ __launch_bounds__(256) void kan_prep(const float* __restrict__ coeff,
                                                const float* __restrict__ gw,
                                                unsigned short* __restrict__ BmT,
                                                float* __restrict__ out) {
  __shared__ float csh[104];
  __shared__ unsigned short tile[16][256];   // [o_loc][il*16+n]
  const int t = threadIdx.x;
  // zero the output (atomic split-K needs zeros); coalesced f4 stores
  {
    const int bid = blockIdx.y * 16 + blockIdx.x;
    float4 z; z.x = z.y = z.z = z.w = 0.f;
    float4* ob = (float4*)out;
#pragma unroll
    for (int j = 0; j < 8; ++j) ob[(size_t)bid * 2048 + j * 256 + t] = z;
  }
  if (t < 104) csh[t] = coeff[t];
  __syncthreads();
  const int otile = blockIdx.x, itile = blockIdx.y;
  const int il = t >> 4, ol = t & 15;
  const int i = itile * 16 + il;
  const int o = otile * 16 + ol;
  const float* g = gw + (size_t)(i * OUT_DIM + o) * 8;
  float4 g0 = *(const float4*)g;
  float4 g1 = *(const float4*)(g + 4);
  float ge[8] = {g0.x, g0.y, g0.z, g0.w, g1.x, g1.y, g1.z, g1.w};
  float mx = ge[0];
#pragma unroll
  for (int e = 1; e < 8; ++e) mx = fmaxf(mx, ge[e]);
  float p[8]; float s = 0.f;
#pragma unroll
  for (int e = 0; e < 8; ++e) { p[e] = __expf(ge[e] - mx); s += p[e]; }
  const float inv = 1.0f / s;
  unsigned short row[16];
#pragma unroll
  for (int n = 0; n < 13; ++n) {
    float w = 0.f;
#pragma unroll
    for (int e = 0; e < 8; ++e) w += p[e] * csh[e * 13 + n];
    row[n] = f2bf(w * inv);
  }
  row[13] = 0; row[14] = 0; row[15] = 0;
  int4* dst = (int4*)&tile[ol][il * 16];
  dst[0] = *(const int4*)&row[0];
  dst[1] = *(const int4*)&row[8];
  __syncthreads();
  const int oo = t >> 4, ck = t & 15;
  int4 v0 = *(const int4*)&tile[oo][ck * 16];
  int4 v1 = *(const int4*)&tile[oo][ck * 16 + 8];
  int4* out4 = (int4*)(BmT + (size_t)(otile * 16 + oo) * KDIM + itile * 256 + ck * 16);
  out4[0] = v0;
  out4[1] = v1;
}

// --- fused basis + GEMM: out[m][o] += A[m][k] * BmT[o][k], k = i*16+n
// A-fragments built DIRECTLY in registers from an LDS-resident x-tile
// (no A staging, no A frag reads). B: double-buffered LDS, covered prefetch,
// one barrier per step. LDS 71680 B -> 2 blocks/CU.
__global__ __launch_bounds__(256, 2) void kan_gemm(const float* __restrict__ x,
                                                   const unsigned short* __restrict__ BmT,
                                                   float* __restrict__ out) {
  extern __shared__ char lds_raw[];
  float* Xsh = (float*)lds_raw;                                  // [TM][XP]
  unsigned short* BshB = (unsigned short*)(lds_raw + XBYTES);    // [2][TN*LDA]

  const int t = threadIdx.x;
  const int lane = t & 63;
  const int wave = t >> 6;
  const int wm = wave & 1, wn = wave >> 1;       // 2x2 waves, 64x64 each
  const int mb = blockIdx.x * TM;
  const int ob = blockIdx.y * TN;
  const int i0 = blockIdx.z * IPER;

  const int lrow = lane & 15;                    // A-frag row within 16
  const int q = lane >> 4;                       // 0..3
  const int iq = q & 1;                          // n-half (dword window)
  const int ih = q >> 1;                         // i offset within kc pair

  // ---- prologue: coalesced x-tile load -> Xsh (256B runs per row)
  {
#pragma unroll
    for (int j = 0; j < 8; ++j) {
      const int id = j * 256 + t;
      const int row = id >> 4, c4 = id & 15;
      float4 v = *(const float4*)(x + (size_t)(mb + row) * IN_DIM + i0 + c4 * 4);
      *(float4*)(Xsh + row * XP + c4 * 4) = v;
    }
  }

  // B loader: 4 rows of 128B per thread, coalesced
  const unsigned short* bsrc[4];
  int bdst[4];
#pragma unroll
  for (int r = 0; r < 4; ++r) {
    int olo = (t >> 3) + 32 * r;
    bsrc[r] = BmT + (size_t)(ob + olo) * KDIM + i0 * NB + (t & 7) * 8;
    bdst[r] = olo * LDA + (t & 7) * 8;
  }

  f32x4 acc[4][4];
#pragma unroll
  for (int a = 0; a < 4; ++a)
#pragma unroll
    for (int b = 0; b < 4; ++b) acc[a][b] = (f32x4){0.f, 0.f, 0.f, 0.f};

  int boff[4];
#pragma unroll
  for (int f = 0; f < 4; ++f)
    boff[f] = (wn * 64 + f * 16 + lrow) * LDA + q * 8;

  // stage B step 0 into buffer 0
  {
    int4 breg[4];
#pragma unroll
    for (int r = 0; r < 4; ++r) breg[r] = *(const int4*)(bsrc[r]);
#pragma unroll
    for (int r = 0; r < 4; ++r) *(int4*)&BshB[bdst[r]] = breg[r];
  }

  __syncthreads();   // Xsh + B buf0 visible

#pragma unroll
  for (int s = 0; s < STEPS; ++s) {
    const int cur = s & 1;
    const bool more = (s + 1 < STEPS);
    // issue next step's B loads NOW; consumed at end of this step (MFMA cover)
    int4 breg[4];
    if (more) {
#pragma unroll
      for (int r = 0; r < 4; ++r) breg[r] = *(const int4*)(bsrc[r] + (s + 1) * BK);
    }
    // MFMA phase: A-frags from registers (spline of Xsh values), B-frags from LDS
    const unsigned short* Bc = BshB + cur * (TN * LDA);
#pragma unroll
    for (int kc = 0; kc < 2; ++kc) {
      const int xcol = s * 4 + kc * 2 + ih;
      short8 af[4], bfr[4];
#pragma unroll
      for (int mf = 0; mf < 4; ++mf) {
        float xv = Xsh[(wm * 64 + mf * 16 + lrow) * XP + xcol];
        af[mf] = make_afrag(xv, iq);
      }
#pragma unroll
      for (int f = 0; f < 4; ++f) bfr[f] = *(const short8*)&Bc[boff[f] + kc * 32];
#pragma unroll
      for (int mf = 0; mf < 4; ++mf)
#pragma unroll
        for (int nf = 0; nf < 4; ++nf)
          acc[mf][nf] = __builtin_amdgcn_mfma_f32_16x16x32_bf16(af[mf], bfr[nf], acc[mf][nf], 0, 0, 0);
    }
    // stage step s+1 into the other buffer
    if (more) {
      unsigned short* Bn = BshB + (1 - cur) * (TN * LDA);
#pragma unroll
      for (int r = 0; r < 4; ++r) *(int4*)&Bn[bdst[r]] = breg[r];
    }
    __syncthreads();   // next buffer complete; readers of cur are done
  }

  // epilogue: split-K accumulate
#pragma unroll
  for (int mf = 0; mf < 4; ++mf)
#pragma unroll
    for (int nf = 0; nf < 4; ++nf)
#pragma unroll
      for (int r = 0; r < 4; ++r) {
        int row = mb + wm * 64 + mf * 16 + (q << 2) + r;
        int col = ob + wn * 64 + nf * 16 + lrow;
        atomicAdd(out + (size_t)row * OUT_DIM + col, acc[mf][nf][r]);
      }
}

extern "C" void kernel_launch(void* const* d_in, const int* in_sizes, int n_in,
                              void* d_out, int out_size, void* d_ws, size_t ws_size,
                              hipStream_t stream) {
  const float* x     = (const float*)d_in[0];   // (4,2048,256) f32
  const float* coeff = (const float*)d_in[1];   // (8,13) f32
  const float* gw    = (const float*)d_in[2];   // (256,256,8) f32
  float* out = (float*)d_out;                   // (4,2048,256) f32
  unsigned short* BmT = (unsigned short*)d_ws;  // 256 x 4096 bf16 = 2 MB

  hipFuncSetAttribute((const void*)kan_gemm,
                      hipFuncAttributeMaxDynamicSharedMemorySize, LDS_TOTAL);
  kan_prep<<<dim3(16, 16), dim3(256), 0, stream>>>(coeff, gw, BmT, out);
  dim3 grid(8192 / TM, OUT_DIM / TN, KSPLIT);
  kan_gemm<<<grid, dim3(256), LDS_TOTAL, stream>>>(x, BmT, out);
}

// Round 10
// 125.202 us; speedup vs baseline: 1.0693x; 1.0693x over previous
//
#include <hip/hip_runtime.h>
#include <hip/hip_bf16.h>

typedef __attribute__((ext_vector_type(8))) short short8;
typedef __attribute__((ext_vector_type(4))) float f32x4;

#define IN_DIM 256
#define OUT_DIM 256
#define NB 16                 // padded basis count (13 real + 3 zero)
#define KDIM (IN_DIM * NB)    // 4096
#define TM 128
#define TN 128
#define KSPLIT 4
#define IPER (IN_DIM / KSPLIT)   // 64 i-values per block
#define STEPS (IPER / 4)         // 16 (4 i's per step)
#define XP 68                    // Xsh pitch in f32 (b128-aligned rows, <=2-way banks)

__device__ __forceinline__ unsigned short f2bf(float f) {
  union { float f; unsigned int u; } v; v.f = f;
  unsigned int r = v.u + 0x7fffu + ((v.u >> 16) & 1u);  // RNE
  return (unsigned short)(r >> 16);
}

__device__ __forceinline__ unsigned pk2(float lo, float hi) {
  union { __hip_bfloat162 h; unsigned u; } cv;
  cv.h = __float22bfloat162_rn(make_float2(lo, hi));
  return cv.u;
}

// Direct-register A-fragment for mfma_f32_16x16x32_bf16 (verified in R9).
// Lane's 8 k-slots = dword window [iq*4, iq*4+4) of the 16-slot spline row.
__device__ __forceinline__ short8 make_afrag(float xv, int iq) {
  float xc = fminf(fmaxf(xv, -1.0f), 1.0f - 1e-6f);
  float u = (xc + 1.0f) * 5.0f;            // h = 0.2
  int c = (int)u;
  c = c > 9 ? 9 : (c < 0 ? 0 : c);
  float tt = u - (float)c;
  float omt = 1.0f - tt;
  float t2 = tt * tt, t3 = t2 * tt;
  float b0 = omt * omt * omt * (1.0f / 6.0f);
  float b1 = (3.0f * t3 - 6.0f * t2 + 4.0f) * (1.0f / 6.0f);
  float b2 = (-3.0f * t3 + 3.0f * t2 + 3.0f * tt + 1.0f) * (1.0f / 6.0f);
  float b3 = t3 * (1.0f / 6.0f);
  unsigned p01 = pk2(b0, b1), p23 = pk2(b2, b3);
  unsigned q0 = pk2(0.0f, b0), q12 = pk2(b1, b2), q3 = pk2(b3, 0.0f);
  const bool odd = (c & 1) != 0;
  const int a = c >> 1;                    // first nonzero dword
  unsigned A0 = odd ? q0 : p01;
  unsigned A1 = odd ? q12 : p23;
  unsigned A2 = odd ? q3 : 0u;
  union { unsigned u4[4]; short8 v; } r;
  const int base = iq * 4;
#pragma unroll
  for (int j = 0; j < 4; ++j) {
    int d = base + j - a;
    unsigned v = (d == 0) ? A0 : 0u;
    v = (d == 1) ? A1 : v;
    v = (d == 2) ? A2 : v;
    r.u4[j] = v;
  }
  return r.v;
}

// --- prep: fold softmax(gating) with coeff, write B2 in MFMA-frag-swizzled
// order so the GEMM's B loads are lane-linear coalesced 1KB reads. Also zeroes out.
// B2 byte offset for (o, i, iq-half):
//   ((((o>>7)*64 + (i>>2))*2 + ((o>>6)&1))*4 + ((o>>4)&3))*2 + ((i>>1)&1)) * 1024
//   + ((i&1)*32 + iq*16 + (o&15)) * 16
__global__ __launch_bounds__(256) void kan_prep(const float* __restrict__ coeff,
                                                const float* __restrict__ gw,
                                                unsigned short* __restrict__ B2,
                                                float* __restrict__ out) {
  __shared__ float csh[104];
  const int t = threadIdx.x;
  // zero the output (atomic split-K needs zeros); coalesced f4 stores
  {
    const int bid = blockIdx.y * 16 + blockIdx.x;
    float4 z; z.x = z.y = z.z = z.w = 0.f;
    float4* ob = (float4*)out;
#pragma unroll
    for (int j = 0; j < 8; ++j) ob[(size_t)bid * 2048 + j * 256 + t] = z;
  }
  if (t < 104) csh[t] = coeff[t];
  __syncthreads();
  const int otile = blockIdx.x, itile = blockIdx.y;
  const int il = t >> 4, ol = t & 15;
  const int i = itile * 16 + il;
  const int o = otile * 16 + ol;
  const float* g = gw + (size_t)(i * OUT_DIM + o) * 8;
  float4 g0 = *(const float4*)g;
  float4 g1 = *(const float4*)(g + 4);
  float ge[8] = {g0.x, g0.y, g0.z, g0.w, g1.x, g1.y, g1.z, g1.w};
  float mx = ge[0];
#pragma unroll
  for (int e = 1; e < 8; ++e) mx = fmaxf(mx, ge[e]);
  float p[8]; float s = 0.f;
#pragma unroll
  for (int e = 0; e < 8; ++e) { p[e] = __expf(ge[e] - mx); s += p[e]; }
  const float inv = 1.0f / s;
  union { unsigned short row[16]; int4 v4[2]; } rb;
#pragma unroll
  for (int n = 0; n < 13; ++n) {
    float w = 0.f;
#pragma unroll
    for (int e = 0; e < 8; ++e) w += p[e] * csh[e * 13 + n];
    rb.row[n] = f2bf(w * inv);
  }
  rb.row[13] = 0; rb.row[14] = 0; rb.row[15] = 0;
  size_t off = ((((size_t)(o >> 7) * 64 + (i >> 2)) * 2 + ((o >> 6) & 1)) * 4 +
                ((o >> 4) & 3)) * 2 + ((i >> 1) & 1);
  off = off * 1024 + ((size_t)(i & 1) * 32 + (o & 15)) * 16;
  char* dst = (char*)B2 + off;
  *(int4*)dst = rb.v4[0];           // iq=0 half
  *(int4*)(dst + 256) = rb.v4[1];   // iq=1 half
}

// --- fused basis + GEMM, BARRIER-FREE K-loop:
// A-frags built in registers (spline of LDS-resident x-tile), B-frags loaded
// directly from L2-resident swizzled B2 (coalesced 1KB/instr), register
// double-buffered one step ahead. No __syncthreads after the prologue.
__global__ __launch_bounds__(256, 2) void kan_gemm(const float* __restrict__ x,
                                                   const unsigned short* __restrict__ B2,
                                                   float* __restrict__ out) {
  __shared__ float Xsh[TM * XP];   // 34816 B

  const int t = threadIdx.x;
  const int lane = t & 63;
  const int wave = t >> 6;
  const int wm = wave & 1, wn = wave >> 1;       // 2x2 waves, 64x64 each
  const int mb = blockIdx.x * TM;
  const int otile = blockIdx.y;                  // o-tile of 128
  const int i0 = blockIdx.z * IPER;

  const int lrow = lane & 15;
  const int q = lane >> 4;                       // 0..3
  const int iq = q & 1;                          // k-dword window half
  const int ih = q >> 1;                         // i offset within kc pair

  // ---- prologue: coalesced x-tile load -> Xsh
  {
#pragma unroll
    for (int j = 0; j < 8; ++j) {
      const int id = j * 256 + t;
      const int row = id >> 4, c4 = id & 15;
      float4 v = *(const float4*)(x + (size_t)(mb + row) * IN_DIM + i0 + c4 * 4);
      *(float4*)(Xsh + row * XP + c4 * 4) = v;
    }
  }

  // B2 fragment base pointers per f (kc via +1024, step via +16384 bytes)
  const char* bp[4];
#pragma unroll
  for (int f = 0; f < 4; ++f) {
    size_t blk = (((size_t)otile * 64 + (i0 >> 2)) * 2 + wn) * 4 + f;
    bp[f] = (const char*)B2 + blk * 2048 + lane * 16;
  }

  f32x4 acc[4][4];
#pragma unroll
  for (int a = 0; a < 4; ++a)
#pragma unroll
    for (int b = 0; b < 4; ++b) acc[a][b] = (f32x4){0.f, 0.f, 0.f, 0.f};

  // prefetch step 0 B-frags
  int4 breg[2][4];
#pragma unroll
  for (int kc = 0; kc < 2; ++kc)
#pragma unroll
    for (int f = 0; f < 4; ++f)
      breg[kc][f] = *(const int4*)(bp[f] + kc * 1024);

  __syncthreads();   // Xsh visible (the only barrier)

#pragma unroll
  for (int s = 0; s < STEPS; ++s) {
    // prefetch next step's B-frags (no barrier: covered by this step's MFMA+VALU)
    int4 bnxt[2][4];
    if (s + 1 < STEPS) {
#pragma unroll
      for (int kc = 0; kc < 2; ++kc)
#pragma unroll
        for (int f = 0; f < 4; ++f)
          bnxt[kc][f] = *(const int4*)(bp[f] + (s + 1) * 16384 + kc * 1024);
    }
#pragma unroll
    for (int kc = 0; kc < 2; ++kc) {
      const int xcol = s * 4 + kc * 2 + ih;
      short8 af[4];
#pragma unroll
      for (int mf = 0; mf < 4; ++mf) {
        float xv = Xsh[(wm * 64 + mf * 16 + lrow) * XP + xcol];
        af[mf] = make_afrag(xv, iq);
      }
#pragma unroll
      for (int mf = 0; mf < 4; ++mf)
#pragma unroll
        for (int nf = 0; nf < 4; ++nf) {
          short8 bf = *(const short8*)&breg[kc][nf];
          acc[mf][nf] = __builtin_amdgcn_mfma_f32_16x16x32_bf16(af[mf], bf, acc[mf][nf], 0, 0, 0);
        }
    }
#pragma unroll
    for (int kc = 0; kc < 2; ++kc)
#pragma unroll
      for (int f = 0; f < 4; ++f)
        breg[kc][f] = bnxt[kc][f];
  }

  // epilogue: split-K accumulate
#pragma unroll
  for (int mf = 0; mf < 4; ++mf)
#pragma unroll
    for (int nf = 0; nf < 4; ++nf)
#pragma unroll
      for (int r = 0; r < 4; ++r) {
        int row = mb + wm * 64 + mf * 16 + (q << 2) + r;
        int col = otile * TN + wn * 64 + nf * 16 + lrow;
        atomicAdd(out + (size_t)row * OUT_DIM + col, acc[mf][nf][r]);
      }
}

extern "C" void kernel_launch(void* const* d_in, const int* in_sizes, int n_in,
                              void* d_out, int out_size, void* d_ws, size_t ws_size,
                              hipStream_t stream) {
  const float* x     = (const float*)d_in[0];   // (4,2048,256) f32
  const float* coeff = (const float*)d_in[1];   // (8,13) f32
  const float* gw    = (const float*)d_in[2];   // (256,256,8) f32
  float* out = (float*)d_out;                   // (4,2048,256) f32
  unsigned short* B2 = (unsigned short*)d_ws;   // 2 MB swizzled B

  kan_prep<<<dim3(16, 16), dim3(256), 0, stream>>>(coeff, gw, B2, out);
  dim3 grid(8192 / TM, OUT_DIM / TN, KSPLIT);
  kan_gemm<<<grid, dim3(256), 0, stream>>>(x, B2, out);
}